// Round 1
// baseline (778.704 us; speedup 1.0000x reference)
//
#include <hip/hip_runtime.h>

// BaseTextureDiffusion: out[b,c,y,x] = sum_k w[b,c,k,y,x] * latent_pad[b,c,y+i-3,x+j-3]
// B=2 C=24 H=W=256 R=7 (replicate pad 3). Memory-bound on the 616 MB weights stream.
//
// v2 restructure vs the 377us/1.7TB/s kernel:
//  - plain (cached) weight loads: __builtin_nontemporal_load removed -- the poison
//    fill in the same capture sustains 6.5 TB/s with ordinary requests; nt was the
//    only nonstandard attribute on the stream that ran at 1.7 TB/s.
//  - TILE_H=8, 2 output rows per thread: 98 weight loads/thread in 14-deep
//    independent batches (vs 7), LDS row reads 24/thread for 2 rows (vs 2x21),
//    1536 blocks (vs 3072) so staging+barrier prologue amortizes 2x.
//  - float4 staging: each wave stages a full 1KB latent row per iteration;
//    halo-4 layout (stride 272 floats) keeps ds_write_b128 and the 3x ds_read_b128
//    window reads all 16B-aligned.

typedef float fx4 __attribute__((ext_vector_type(4)));

constexpr int Hh = 256, Ww = 256, Rr = 7, PAD = 3;
constexpr int TILE_H  = 8;
constexpr int LH      = TILE_H + 2 * PAD;   // 14 latent rows staged
constexpr int LWP     = 272;                // floats per LDS row: 16B multiple
constexpr int COL0    = 4;                  // LDS col holding global x=0 (halo-4)
constexpr int TILES_Y = Hh / TILE_H;        // 32
constexpr int PLANES  = 48;                 // B*C

__global__ __launch_bounds__(256) void diffusion_kernel(
    const float* __restrict__ latent,
    const float* __restrict__ weights,
    float* __restrict__ out)
{
    __shared__ __align__(16) float lds[LH * LWP];   // 15.2 KB

    const int bid   = blockIdx.x;
    const int plane = bid / TILES_Y;                // b*C + c
    const int ty0   = (bid % TILES_Y) * TILE_H;

    const float* lat  = latent  + (size_t)plane * Hh * Ww;
    const float* wgt  = weights + (size_t)plane * (Rr * Rr) * Hh * Ww;
    float*       optr = out     + (size_t)plane * Hh * Ww;

    // ---- Stage latent rows [ty0-3, ty0+8+3) ----
    // Interior: 14 rows x 64 float4; wave w stages row w each pass (1KB contiguous).
    for (int idx = threadIdx.x; idx < LH * 64; idx += 256) {
        const int ly = idx >> 6;
        const int q  = idx & 63;
        const int gy = min(max(ty0 + ly - PAD, 0), Hh - 1);
        const fx4 v  = *(const fx4*)(lat + (size_t)gy * Ww + 4 * q);
        *(fx4*)(&lds[ly * LWP + COL0 + 4 * q]) = v;
    }
    // Halo: cols 1..3 replicate x=0, cols 260..262 replicate x=255.
    if (threadIdx.x < LH * 6) {
        const int ly  = threadIdx.x / 6;
        const int h   = threadIdx.x % 6;
        const int gy  = min(max(ty0 + ly - PAD, 0), Hh - 1);
        const int col = (h < 3) ? (1 + h) : (257 + h);   // 1..3 or 260..262
        const int gx  = (h < 3) ? 0 : (Ww - 1);
        lds[ly * LWP + col] = lat[(size_t)gy * Ww + gx];
    }
    __syncthreads();

    // ---- Compute: wave wy owns output rows {ty0+2*wy, ty0+2*wy+1} ----
    const int tx = threadIdx.x & 63;
    const int wy = threadIdx.x >> 6;
    const int x  = 4 * tx;
    const int r0 = ty0 + 2 * wy;

    const float* w0 = wgt + (size_t)r0 * Ww + x;   // row r0 weights, k-stride 64K floats
    const float* w1 = w0 + Ww;                     // row r0+1

    fx4 acc0 = {0.f, 0.f, 0.f, 0.f};
    fx4 acc1 = {0.f, 0.f, 0.f, 0.f};

    // LDS rows needed: output row r0 window i -> lds row 2*wy+i (i=0..6),
    // row r0+1 window i -> lds row 2*wy+1+i. Union: ii = 0..7.
    #pragma unroll
    for (int ii = 0; ii < 8; ++ii) {
        const float* lrow = &lds[(2 * wy + ii) * LWP + x];  // col x = 4*tx, 16B aligned
        const fx4 a = *(const fx4*)(lrow);
        const fx4 b = *(const fx4*)(lrow + 4);
        const fx4 c = *(const fx4*)(lrow + 8);
        // l[m] = latent_pad value at col x + m - 4; window uses l[1..10].
        const float l[12] = {a.x, a.y, a.z, a.w, b.x, b.y, b.z, b.w, c.x, c.y, c.z, c.w};

        // Batch all (up to 14) independent weight loads before consuming.
        fx4 wa[7], wb[7];
        if (ii < 7) {
            #pragma unroll
            for (int j = 0; j < 7; ++j)
                wa[j] = *(const fx4*)(w0 + (size_t)(ii * 7 + j) * (Hh * Ww));
        }
        if (ii >= 1) {
            #pragma unroll
            for (int j = 0; j < 7; ++j)
                wb[j] = *(const fx4*)(w1 + (size_t)((ii - 1) * 7 + j) * (Hh * Ww));
        }
        if (ii < 7) {
            #pragma unroll
            for (int j = 0; j < 7; ++j) {    // k = ii*7+j, ascending (matches ref order)
                acc0.x += wa[j].x * l[j + 1];
                acc0.y += wa[j].y * l[j + 2];
                acc0.z += wa[j].z * l[j + 3];
                acc0.w += wa[j].w * l[j + 4];
            }
        }
        if (ii >= 1) {
            #pragma unroll
            for (int j = 0; j < 7; ++j) {    // k = (ii-1)*7+j, ascending
                acc1.x += wb[j].x * l[j + 1];
                acc1.y += wb[j].y * l[j + 2];
                acc1.z += wb[j].z * l[j + 3];
                acc1.w += wb[j].w * l[j + 4];
            }
        }
    }

    __builtin_nontemporal_store(acc0, (fx4*)(optr + (size_t)r0 * Ww + x));
    __builtin_nontemporal_store(acc1, (fx4*)(optr + (size_t)(r0 + 1) * Ww + x));
}

extern "C" void kernel_launch(void* const* d_in, const int* in_sizes, int n_in,
                              void* d_out, int out_size, void* d_ws, size_t ws_size,
                              hipStream_t stream) {
    const float* latent  = (const float*)d_in[0];
    const float* weights = (const float*)d_in[1];
    // d_in[2] = window_size (scalar int, fixed at 7) -- compiled in.
    float* out = (float*)d_out;

    const int nblocks = PLANES * TILES_Y;  // 1536
    diffusion_kernel<<<nblocks, 256, 0, stream>>>(latent, weights, out);
}